// Round 11
// baseline (90.025 us; speedup 1.0000x reference)
//
#include <hip/hip_runtime.h>
#include <math.h>

// Base = R21 (80.7us, absmax 0.0 -- best). R22 = R21 with two micro-shaves,
// everything else bit-identical:
//  (1) P2 pair-reduce: __shfl_xor(v,1) (ds_bpermute, LDS pipe; 12/thread)
//      -> dpp_add<0xB1> quad_perm[1,0,3,2] (pure VALU). Exact butterfly,
//      all quads fully active (tid<192). Validated pattern (R12: absmax 0.0).
//  (2) 8 images/block (4 pairs), grid 512. Same LDS buffers (24.9KB, pairs
//      reuse 2-slice sc1/sc2) -> same 4 blocks/CU x 16 waves. trig2 staged
//      once per 8 images; P3+P1 mixed interval 3x per block (was 1x).
// Lesson bank: restructures regress (R12/R16/R20); pipe-offload micro-shaves
// pay (R21: -1.4us). Warm compute ~13us vs ~60us uncontrollable harness
// floor (42us poison fill + precompute + gaps).
//
// d_ws trig layout (float2 = {cos,sin}):
//   [0,2880)    fft:   [n*288 + k]            (transposed ff_w trig)
//   [2880,3400) trig2: [ocp*130 + e*2 + (oc&1)], e = ch*16+ki*4+kj (pad 130)
//   [3400,3416) trig1: [oc*4 + e], e = a*2+c
#define FFT_OFF 0
#define W2_OFF 2880
#define W1_OFF 3400

__global__ void precompute_trig(const float* __restrict__ w1,
                                const float* __restrict__ w2,
                                const float* __restrict__ ff,
                                float2* __restrict__ ws) {
    int idx = blockIdx.x * blockDim.x + threadIdx.x;
    if (idx < 2880) {
        int k = idx / 10, n = idx % 10;
        float s, c; __sincosf(ff[idx], &s, &c);
        ws[FFT_OFF + n * 288 + k] = make_float2(c, s);
    } else if (idx < 3392) {
        int i = idx - 2880;                  // i = oc*64 + e
        int oc = i >> 6, e = i & 63;
        float s, c; __sincosf(w2[i], &s, &c);
        ws[W2_OFF + (oc >> 1) * 130 + e * 2 + (oc & 1)] = make_float2(c, s);
    } else if (idx < 3408) {
        int i = idx - 3392;
        float s, c; __sincosf(w1[i], &s, &c);
        ws[W1_OFF + i] = make_float2(c, s);
    }
}

// One conv1 output position: 4 sincos + 4 oc x (16 fma + rsqrt).
// Bitwise identical to R11's per-position phase-1 body.
__device__ __forceinline__ void conv1_pos(float2 r0, float2 r1,
                                          const float2* __restrict__ w1t,
                                          float2* __restrict__ sc1,
                                          int pi, int pj) {
    float sx[4], cx[4];
    __sincosf(r0.x, &sx[0], &cx[0]);
    __sincosf(r0.y, &sx[1], &cx[1]);
    __sincosf(r1.x, &sx[2], &cx[2]);
    __sincosf(r1.y, &sx[3], &cx[3]);
    #pragma unroll
    for (int oc = 0; oc < 4; oc++) {
        float4 wa = *(const float4*)(w1t + oc * 4);      // taps e0,e1 (uniform)
        float4 wb = *(const float4*)(w1t + oc * 4 + 2);  // taps e2,e3 (uniform)
        float Y = 0.f, X = 0.f;
        Y = fmaf(sx[0], wa.x, fmaf(-cx[0], wa.y, Y));
        X = fmaf(cx[0], wa.x, fmaf( sx[0], wa.y, X));
        Y = fmaf(sx[1], wa.z, fmaf(-cx[1], wa.w, Y));
        X = fmaf(cx[1], wa.z, fmaf( sx[1], wa.w, X));
        Y = fmaf(sx[2], wb.x, fmaf(-cx[2], wb.y, Y));
        X = fmaf(cx[2], wb.x, fmaf( sx[2], wb.y, X));
        Y = fmaf(sx[3], wb.z, fmaf(-cx[3], wb.w, Y));
        X = fmaf(cx[3], wb.z, fmaf( sx[3], wb.w, X));
        float inv = rsqrtf(fmaxf(fmaf(X, X, Y * Y), 1e-30f));
        sc1[oc * 252 + pi * 18 + pj] = make_float2(Y * inv, X * inv);
    }
}

// DPP add helper (pure VALU, zero LDS-pipe traffic). CTRL = HW immediate.
template <int CTRL>
__device__ __forceinline__ float dpp_add(float v) {
    return v + __int_as_float(__builtin_amdgcn_mov_dpp(
                   __float_as_int(v), CTRL, 0xF, 0xF, true));
}
// 32-lane sum (validated absmax 0.0 in R20/R21): row_shr 1/2/4/8 builds
// 16-lane row sums at lanes 15/31/47/63; row_bcast15 adds each even row's
// lane15 into the next row -> lanes 31 and 63 hold their 32-half's total.
__device__ __forceinline__ float reduce32(float v) {
    v = dpp_add<0x111>(v);  // row_shr:1
    v = dpp_add<0x112>(v);  // row_shr:2
    v = dpp_add<0x114>(v);  // row_shr:4
    v = dpp_add<0x118>(v);  // row_shr:8
    v = dpp_add<0x142>(v);  // row_bcast:15
    return v;
}

// 256 threads = 4 waves, 8 images/block (4 pairs), grid B/8 = 512.
__global__ __launch_bounds__(256, 4) void ringnn_kernel(
    const float* __restrict__ x,
    const float2* __restrict__ ws,
    float* __restrict__ out)
{
    __shared__ __align__(16) float2 trig2[520];
    __shared__ __align__(16) float2 sc1[2 * 1008]; // img*1008 + ch*252 + row*18 + col
    __shared__ __align__(16) float2 sc2[2 * 288];  // img*288 + p*8 + oc
    const int tid = threadIdx.x;
    const float2* __restrict__ fft = ws + FFT_OFF;
    const float2* __restrict__ w1t = ws + W1_OFF;
    const size_t imgBase = (size_t)blockIdx.x * 8;

    // ---- per-thread position maps (constant across pairs) ----
    const int im0 = (tid >= 196) ? 1 : 0;
    const int p0  = tid - im0 * 196;
    const int pi0 = p0 / 14, pj0 = p0 % 14;
    const int pr1 = tid + 60;                   // img1 pos for round 1 (tid<136)
    const int pi1 = pr1 / 14, pj1 = pr1 % 14;

    float2 a0, a1, b0 = make_float2(0.f, 0.f), b1 = make_float2(0.f, 0.f);

    auto loadPair = [&](size_t pairImg) {
        const float* xb0 = x + (pairImg + im0) * 784;
        a0 = *(const float2*)(xb0 + (2 * pi0) * 28 + 2 * pj0);
        a1 = *(const float2*)(xb0 + (2 * pi0 + 1) * 28 + 2 * pj0);
        if (tid < 136) {
            const float* xb1 = x + (pairImg + 1) * 784;
            b0 = *(const float2*)(xb1 + (2 * pi1) * 28 + 2 * pj1);
            b1 = *(const float2*)(xb1 + (2 * pi1 + 1) * 28 + 2 * pj1);
        }
    };

    // phase 1: 392 tasks in 2 rounds; per-position math bitwise = R11.
    auto phase1 = [&]() {
        conv1_pos(a0, a1, w1t, sc1 + im0 * 1008, pi0, pj0);
        if (tid < 136) conv1_pos(b0, b1, w1t, sc1 + 1008, pi1, pj1);
    };

    // phase 2: 192 tasks = (img, oi, ojg, ocp, hf); per-task code = R11
    // except the pair-butterfly is DPP quad_perm (R22), not shfl_xor.
    auto phase2 = [&]() {
        if (tid < 192) {
            const int img = (tid >= 96) ? 1 : 0;
            int r = tid - img * 96;
            int oi = r >> 4, ojg = (r >> 3) & 1, ocp = (r >> 1) & 3, hf = r & 1;
            const float2* wbp = trig2 + ocp * 130;
            const float2* s1p = sc1 + img * 1008;
            float aY[3][2] = {{0.f,0.f},{0.f,0.f},{0.f,0.f}};
            float aX[3][2] = {{0.f,0.f},{0.f,0.f},{0.f,0.f}};
            #pragma unroll
            for (int ch = 0; ch < 4; ch++) {
                #pragma unroll
                for (int kk = 0; kk < 2; kk++) {
                    int ki = hf * 2 + kk;
                    int base = ch * 252 + (oi * 2 + ki) * 18 + ojg * 6;
                    float4 f0 = *(const float4*)(s1p + base);
                    float4 f1 = *(const float4*)(s1p + base + 2);
                    float4 f2 = *(const float4*)(s1p + base + 4);
                    float4 f3 = *(const float4*)(s1p + base + 6);
                    float ss[8] = {f0.x,f0.z,f1.x,f1.z,f2.x,f2.z,f3.x,f3.z};
                    float cc[8] = {f0.y,f0.w,f1.y,f1.w,f2.y,f2.w,f3.y,f3.w};
                    int e0 = ch * 16 + ki * 4;
                    #pragma unroll
                    for (int kj = 0; kj < 4; kj++) {
                        float4 wv = *(const float4*)(wbp + (e0 + kj) * 2); // (c0,s0,c1,s1)
                        #pragma unroll
                        for (int ojl = 0; ojl < 3; ojl++) {
                            float s = ss[ojl * 2 + kj], c = cc[ojl * 2 + kj];
                            aY[ojl][0] = fmaf(s, wv.x, fmaf(-c, wv.y, aY[ojl][0]));
                            aX[ojl][0] = fmaf(c, wv.x, fmaf( s, wv.y, aX[ojl][0]));
                            aY[ojl][1] = fmaf(s, wv.z, fmaf(-c, wv.w, aY[ojl][1]));
                            aX[ojl][1] = fmaf(c, wv.z, fmaf( s, wv.w, aX[ojl][1]));
                        }
                    }
                }
            }
            // hf butterfly: even/odd lane pairs (never straddle images).
            // DPP quad_perm[1,0,3,2] add == shfl_xor(,1) add, pure VALU.
            #pragma unroll
            for (int ojl = 0; ojl < 3; ojl++) {
                float y0 = dpp_add<0xB1>(aY[ojl][0]);
                float y1 = dpp_add<0xB1>(aY[ojl][1]);
                float x0 = dpp_add<0xB1>(aX[ojl][0]);
                float x1 = dpp_add<0xB1>(aX[ojl][1]);
                float Y = hf ? y1 : y0;
                float X = hf ? x1 : x0;
                float inv = rsqrtf(fmaxf(fmaf(X, X, Y * Y), 1e-30f));
                int p = oi * 6 + ojg * 3 + ojl;
                sc2[img * 288 + p * 8 + ocp * 2 + hf] = make_float2(Y * inv, X * inv);
            }
        }
    };

    // phase 3: 640 tasks = (img, n, s32) in 3 rounds; DPP reduce (R21).
    auto phase3 = [&](size_t pairImg) {
        #pragma unroll
        for (int rr = 0; rr < 3; rr++) {
            int t = tid + (rr << 8);
            if (t < 640) {
                int img = (t >= 320) ? 1 : 0;
                int idx = t - img * 320;
                int n = idx >> 5, s = idx & 31;
                const float2* wn = fft + n * 288;
                const float2* s2p = sc2 + img * 288;
                float Y = 0.f, X = 0.f;
                #pragma unroll
                for (int i = 0; i < 9; i++) {
                    int k = i * 32 + s;
                    float2 sc = s2p[k];
                    float2 w = wn[k];
                    Y = fmaf(sc.x, w.x, fmaf(-sc.y, w.y, Y));
                    X = fmaf(sc.y, w.x, fmaf( sc.x, w.y, X));
                }
                Y = reduce32(Y);
                X = reduce32(X);
                if (s == 31) {
                    out[(pairImg + img) * 10 + n] =
                        Y * rsqrtf(fmaxf(fmaf(X, X, Y * Y), 1e-30f));
                }
            }
        }
    };

    // ---- persistent 8-image schedule (4 pairs, software-pipelined) ----
    loadPair(imgBase);
    for (int i = tid; i < 260; i += 256)                 // trig2: once per block
        ((float4*)trig2)[i] = ((const float4*)(ws + W2_OFF))[i];
    phase1();
    __syncthreads();              // trig2 staged + pair0 sc1 ready
    #pragma unroll
    for (int p = 0; p < 4; p++) {
        phase2();
        __syncthreads();          // pair p sc2 ready; sc1 free
        if (p < 3) loadPair(imgBase + 2 * (p + 1));  // next x-loads hide under P3
        phase3(imgBase + 2 * p);  // reads sc2 (pair p)
        if (p < 3) {
            phase1();             // writes sc1 (pair p+1) -- disjoint from P3
            __syncthreads();      // pair p+1 sc1 ready; sc2 free
        }
    }
}

extern "C" void kernel_launch(void* const* d_in, const int* in_sizes, int n_in,
                              void* d_out, int out_size, void* d_ws, size_t ws_size,
                              hipStream_t stream) {
    const float* x  = (const float*)d_in[0];
    const float* w1 = (const float*)d_in[1];
    const float* w2 = (const float*)d_in[2];
    const float* ff = (const float*)d_in[3];
    float* out = (float*)d_out;
    const int B = in_sizes[0] / 784;   // 4096

    float2* ws = (float2*)d_ws;
    precompute_trig<<<14, 256, 0, stream>>>(w1, w2, ff, ws);
    ringnn_kernel<<<B / 8, 256, 0, stream>>>(x, ws, out);   // 512 = 2 blocks/CU resident wavefronts x4
}

// Round 12
// 80.783 us; speedup vs baseline: 1.1144x; 1.1144x over previous
//
#include <hip/hip_runtime.h>
#include <math.h>

// Base = R21 (80.7us, absmax 0.0 -- best). R23 = R21 + ONE isolated change:
//  P2 pair-reduce: __shfl_xor(v,1) (ds_bpermute, LDS pipe; 12/thread) ->
//  dpp_add<0xB1> quad_perm[1,0,3,2] (pure VALU). Exact butterfly; validated
//  numerically in R22 (absmax 0.0).
// R22 post-mortem: its regression (90.0) was the grid halving to 512 ->
// 2 blocks/CU resident (grid-limited). Matches R20's 90.3 at 2 blocks/CU:
// residency 2/CU costs ~8-9us. R23 restores grid 1024 / 4 img/block /
// 4 blocks/CU (16 waves/CU) and keeps only the pipe-offload shave.
//
// d_ws trig layout (float2 = {cos,sin}):
//   [0,2880)    fft:   [n*288 + k]            (transposed ff_w trig)
//   [2880,3400) trig2: [ocp*130 + e*2 + (oc&1)], e = ch*16+ki*4+kj (pad 130)
//   [3400,3416) trig1: [oc*4 + e], e = a*2+c
#define FFT_OFF 0
#define W2_OFF 2880
#define W1_OFF 3400

__global__ void precompute_trig(const float* __restrict__ w1,
                                const float* __restrict__ w2,
                                const float* __restrict__ ff,
                                float2* __restrict__ ws) {
    int idx = blockIdx.x * blockDim.x + threadIdx.x;
    if (idx < 2880) {
        int k = idx / 10, n = idx % 10;
        float s, c; __sincosf(ff[idx], &s, &c);
        ws[FFT_OFF + n * 288 + k] = make_float2(c, s);
    } else if (idx < 3392) {
        int i = idx - 2880;                  // i = oc*64 + e
        int oc = i >> 6, e = i & 63;
        float s, c; __sincosf(w2[i], &s, &c);
        ws[W2_OFF + (oc >> 1) * 130 + e * 2 + (oc & 1)] = make_float2(c, s);
    } else if (idx < 3408) {
        int i = idx - 3392;
        float s, c; __sincosf(w1[i], &s, &c);
        ws[W1_OFF + i] = make_float2(c, s);
    }
}

// One conv1 output position: 4 sincos + 4 oc x (16 fma + rsqrt).
// Bitwise identical to R11's per-position phase-1 body.
__device__ __forceinline__ void conv1_pos(float2 r0, float2 r1,
                                          const float2* __restrict__ w1t,
                                          float2* __restrict__ sc1,
                                          int pi, int pj) {
    float sx[4], cx[4];
    __sincosf(r0.x, &sx[0], &cx[0]);
    __sincosf(r0.y, &sx[1], &cx[1]);
    __sincosf(r1.x, &sx[2], &cx[2]);
    __sincosf(r1.y, &sx[3], &cx[3]);
    #pragma unroll
    for (int oc = 0; oc < 4; oc++) {
        float4 wa = *(const float4*)(w1t + oc * 4);      // taps e0,e1 (uniform)
        float4 wb = *(const float4*)(w1t + oc * 4 + 2);  // taps e2,e3 (uniform)
        float Y = 0.f, X = 0.f;
        Y = fmaf(sx[0], wa.x, fmaf(-cx[0], wa.y, Y));
        X = fmaf(cx[0], wa.x, fmaf( sx[0], wa.y, X));
        Y = fmaf(sx[1], wa.z, fmaf(-cx[1], wa.w, Y));
        X = fmaf(cx[1], wa.z, fmaf( sx[1], wa.w, X));
        Y = fmaf(sx[2], wb.x, fmaf(-cx[2], wb.y, Y));
        X = fmaf(cx[2], wb.x, fmaf( sx[2], wb.y, X));
        Y = fmaf(sx[3], wb.z, fmaf(-cx[3], wb.w, Y));
        X = fmaf(cx[3], wb.z, fmaf( sx[3], wb.w, X));
        float inv = rsqrtf(fmaxf(fmaf(X, X, Y * Y), 1e-30f));
        sc1[oc * 252 + pi * 18 + pj] = make_float2(Y * inv, X * inv);
    }
}

// DPP add helper (pure VALU, zero LDS-pipe traffic). CTRL = HW immediate.
template <int CTRL>
__device__ __forceinline__ float dpp_add(float v) {
    return v + __int_as_float(__builtin_amdgcn_mov_dpp(
                   __float_as_int(v), CTRL, 0xF, 0xF, true));
}
// 32-lane sum (validated absmax 0.0 in R20/R21): row_shr 1/2/4/8 builds
// 16-lane row sums at lanes 15/31/47/63; row_bcast15 adds each even row's
// lane15 into the next row -> lanes 31 and 63 hold their 32-half's total.
__device__ __forceinline__ float reduce32(float v) {
    v = dpp_add<0x111>(v);  // row_shr:1
    v = dpp_add<0x112>(v);  // row_shr:2
    v = dpp_add<0x114>(v);  // row_shr:4
    v = dpp_add<0x118>(v);  // row_shr:8
    v = dpp_add<0x142>(v);  // row_bcast:15
    return v;
}

// 256 threads = 4 waves, 4 images/block (2 pairs), grid B/4 = 1024.
__global__ __launch_bounds__(256, 4) void ringnn_kernel(
    const float* __restrict__ x,
    const float2* __restrict__ ws,
    float* __restrict__ out)
{
    __shared__ __align__(16) float2 trig2[520];
    __shared__ __align__(16) float2 sc1[2 * 1008]; // img*1008 + ch*252 + row*18 + col
    __shared__ __align__(16) float2 sc2[2 * 288];  // img*288 + p*8 + oc
    const int tid = threadIdx.x;
    const float2* __restrict__ fft = ws + FFT_OFF;
    const float2* __restrict__ w1t = ws + W1_OFF;
    const size_t imgBase = (size_t)blockIdx.x * 4;

    // ---- per-thread position maps (constant across pairs) ----
    const int im0 = (tid >= 196) ? 1 : 0;
    const int p0  = tid - im0 * 196;
    const int pi0 = p0 / 14, pj0 = p0 % 14;
    const int pr1 = tid + 60;                   // img1 pos for round 1 (tid<136)
    const int pi1 = pr1 / 14, pj1 = pr1 % 14;

    float2 a0, a1, b0 = make_float2(0.f, 0.f), b1 = make_float2(0.f, 0.f);

    auto loadPair = [&](size_t pairImg) {
        const float* xb0 = x + (pairImg + im0) * 784;
        a0 = *(const float2*)(xb0 + (2 * pi0) * 28 + 2 * pj0);
        a1 = *(const float2*)(xb0 + (2 * pi0 + 1) * 28 + 2 * pj0);
        if (tid < 136) {
            const float* xb1 = x + (pairImg + 1) * 784;
            b0 = *(const float2*)(xb1 + (2 * pi1) * 28 + 2 * pj1);
            b1 = *(const float2*)(xb1 + (2 * pi1 + 1) * 28 + 2 * pj1);
        }
    };

    // phase 1: 392 tasks in 2 rounds; per-position math bitwise = R11.
    auto phase1 = [&]() {
        conv1_pos(a0, a1, w1t, sc1 + im0 * 1008, pi0, pj0);
        if (tid < 136) conv1_pos(b0, b1, w1t, sc1 + 1008, pi1, pj1);
    };

    // phase 2: 192 tasks = (img, oi, ojg, ocp, hf); per-task code = R11
    // except the pair-butterfly is DPP quad_perm (R23), not shfl_xor.
    auto phase2 = [&]() {
        if (tid < 192) {
            const int img = (tid >= 96) ? 1 : 0;
            int r = tid - img * 96;
            int oi = r >> 4, ojg = (r >> 3) & 1, ocp = (r >> 1) & 3, hf = r & 1;
            const float2* wbp = trig2 + ocp * 130;
            const float2* s1p = sc1 + img * 1008;
            float aY[3][2] = {{0.f,0.f},{0.f,0.f},{0.f,0.f}};
            float aX[3][2] = {{0.f,0.f},{0.f,0.f},{0.f,0.f}};
            #pragma unroll
            for (int ch = 0; ch < 4; ch++) {
                #pragma unroll
                for (int kk = 0; kk < 2; kk++) {
                    int ki = hf * 2 + kk;
                    int base = ch * 252 + (oi * 2 + ki) * 18 + ojg * 6;
                    float4 f0 = *(const float4*)(s1p + base);
                    float4 f1 = *(const float4*)(s1p + base + 2);
                    float4 f2 = *(const float4*)(s1p + base + 4);
                    float4 f3 = *(const float4*)(s1p + base + 6);
                    float ss[8] = {f0.x,f0.z,f1.x,f1.z,f2.x,f2.z,f3.x,f3.z};
                    float cc[8] = {f0.y,f0.w,f1.y,f1.w,f2.y,f2.w,f3.y,f3.w};
                    int e0 = ch * 16 + ki * 4;
                    #pragma unroll
                    for (int kj = 0; kj < 4; kj++) {
                        float4 wv = *(const float4*)(wbp + (e0 + kj) * 2); // (c0,s0,c1,s1)
                        #pragma unroll
                        for (int ojl = 0; ojl < 3; ojl++) {
                            float s = ss[ojl * 2 + kj], c = cc[ojl * 2 + kj];
                            aY[ojl][0] = fmaf(s, wv.x, fmaf(-c, wv.y, aY[ojl][0]));
                            aX[ojl][0] = fmaf(c, wv.x, fmaf( s, wv.y, aX[ojl][0]));
                            aY[ojl][1] = fmaf(s, wv.z, fmaf(-c, wv.w, aY[ojl][1]));
                            aX[ojl][1] = fmaf(c, wv.z, fmaf( s, wv.w, aX[ojl][1]));
                        }
                    }
                }
            }
            // hf butterfly: even/odd lane pairs (never straddle images).
            // DPP quad_perm[1,0,3,2] add == shfl_xor(,1) add, pure VALU.
            #pragma unroll
            for (int ojl = 0; ojl < 3; ojl++) {
                float y0 = dpp_add<0xB1>(aY[ojl][0]);
                float y1 = dpp_add<0xB1>(aY[ojl][1]);
                float x0 = dpp_add<0xB1>(aX[ojl][0]);
                float x1 = dpp_add<0xB1>(aX[ojl][1]);
                float Y = hf ? y1 : y0;
                float X = hf ? x1 : x0;
                float inv = rsqrtf(fmaxf(fmaf(X, X, Y * Y), 1e-30f));
                int p = oi * 6 + ojg * 3 + ojl;
                sc2[img * 288 + p * 8 + ocp * 2 + hf] = make_float2(Y * inv, X * inv);
            }
        }
    };

    // phase 3: 640 tasks = (img, n, s32) in 3 rounds; DPP reduce (R21).
    auto phase3 = [&](size_t pairImg) {
        #pragma unroll
        for (int rr = 0; rr < 3; rr++) {
            int t = tid + (rr << 8);
            if (t < 640) {
                int img = (t >= 320) ? 1 : 0;
                int idx = t - img * 320;
                int n = idx >> 5, s = idx & 31;
                const float2* wn = fft + n * 288;
                const float2* s2p = sc2 + img * 288;
                float Y = 0.f, X = 0.f;
                #pragma unroll
                for (int i = 0; i < 9; i++) {
                    int k = i * 32 + s;
                    float2 sc = s2p[k];
                    float2 w = wn[k];
                    Y = fmaf(sc.x, w.x, fmaf(-sc.y, w.y, Y));
                    X = fmaf(sc.y, w.x, fmaf( sc.x, w.y, X));
                }
                Y = reduce32(Y);
                X = reduce32(X);
                if (s == 31) {
                    out[(pairImg + img) * 10 + n] =
                        Y * rsqrtf(fmaxf(fmaf(X, X, Y * Y), 1e-30f));
                }
            }
        }
    };

    // ---- persistent 4-image schedule (2 pairs, software-pipelined) ----
    loadPair(imgBase);
    for (int i = tid; i < 260; i += 256)                 // trig2: once per block
        ((float4*)trig2)[i] = ((const float4*)(ws + W2_OFF))[i];
    phase1();
    __syncthreads();          // trig2 staged + pair0 sc1 ready
    phase2();
    __syncthreads();          // pair0 sc2 ready; sc1 free
    loadPair(imgBase + 2);    // pair1 x-loads: latency hides under phase3
    phase3(imgBase);          // reads sc2 (pair0)
    phase1();                 // writes sc1 (pair1) -- disjoint from phase3
    __syncthreads();          // pair1 sc1 ready; sc2 free
    phase2();
    __syncthreads();          // pair1 sc2 ready
    phase3(imgBase + 2);
}

extern "C" void kernel_launch(void* const* d_in, const int* in_sizes, int n_in,
                              void* d_out, int out_size, void* d_ws, size_t ws_size,
                              hipStream_t stream) {
    const float* x  = (const float*)d_in[0];
    const float* w1 = (const float*)d_in[1];
    const float* w2 = (const float*)d_in[2];
    const float* ff = (const float*)d_in[3];
    float* out = (float*)d_out;
    const int B = in_sizes[0] / 784;   // 4096

    float2* ws = (float2*)d_ws;
    precompute_trig<<<14, 256, 0, stream>>>(w1, w2, ff, ws);
    ringnn_kernel<<<B / 4, 256, 0, stream>>>(x, ws, out);   // 1024 = 4 blocks/CU
}